// Round 1
// baseline (5221.391 us; speedup 1.0000x reference)
//
#include <hip/hip_runtime.h>
#include <cstdint>
#include <cstddef>

#define NB   4096
#define NN   20
#define DD   256
#define TST  30        // MAX_STEPS = int(20*1.5)
#define RPB  16        // batch rows per block
#define NTHR 512
#define SCALE 0.0625f  // 1/sqrt(256)

__device__ __forceinline__ float sigf(float x) {
    return 1.0f / (1.0f + expf(-x));
}

// ---------------------------------------------------------------------------
// keys[M][256] = node_emb_flat[M][256] @ attn_w[256][256]^T + attn_b,  M = NB*NN
// 64x64 tile, 256 threads, 4x4 micro-tile, KC=32
// ---------------------------------------------------------------------------
__global__ __launch_bounds__(256) void keys_gemm(
    const float* __restrict__ A, const float* __restrict__ W,
    const float* __restrict__ bias, float* __restrict__ C)
{
    __shared__ float As[64][33];
    __shared__ float Bs[64][33];
    const int bm = blockIdx.x * 64;
    const int bn = blockIdx.y * 64;
    const int t  = threadIdx.x;
    const int tm = t >> 4, tn = t & 15;
    const int sr = t >> 3;            // staging row 0..31
    const int sk = (t & 7) << 2;      // staging k offset
    float acc[4][4] = {};
    for (int k0 = 0; k0 < DD; k0 += 32) {
        __syncthreads();
#pragma unroll
        for (int p = 0; p < 2; ++p) {
            const int r = sr + p * 32;
            const float4 va = *(const float4*)&A[(size_t)(bm + r) * DD + k0 + sk];
            As[r][sk] = va.x; As[r][sk + 1] = va.y; As[r][sk + 2] = va.z; As[r][sk + 3] = va.w;
            const float4 vb = *(const float4*)&W[(size_t)(bn + r) * DD + k0 + sk];
            Bs[r][sk] = vb.x; Bs[r][sk + 1] = vb.y; Bs[r][sk + 2] = vb.z; Bs[r][sk + 3] = vb.w;
        }
        __syncthreads();
#pragma unroll
        for (int k = 0; k < 32; ++k) {
            float a[4], b[4];
#pragma unroll
            for (int i = 0; i < 4; ++i) a[i] = As[tm * 4 + i][k];
#pragma unroll
            for (int j = 0; j < 4; ++j) b[j] = Bs[tn * 4 + j][k];
#pragma unroll
            for (int i = 0; i < 4; ++i)
#pragma unroll
                for (int j = 0; j < 4; ++j)
                    acc[i][j] = fmaf(a[i], b[j], acc[i][j]);
        }
    }
#pragma unroll
    for (int i = 0; i < 4; ++i) {
        const int row = bm + tm * 4 + i;
#pragma unroll
        for (int j = 0; j < 4; ++j) {
            const int col = bn + tn * 4 + j;
            C[(size_t)row * DD + col] = acc[i][j] + bias[col];
        }
    }
}

// ---------------------------------------------------------------------------
// Persistent decoder: 256 blocks x 16 batch rows, 512 threads (8 waves).
// Per step: gates[16,1024] = xcat[16,512] @ Wcat^T  (Wcat = [W_ih | W_hh]),
// then LSTM elementwise, done-predictor, pointer scores vs precomputed keys,
// masked softmax + argmax, state update, next-input gather. All in LDS.
// ---------------------------------------------------------------------------
__global__ __launch_bounds__(512) void decode(
    const float* __restrict__ ne,    // [NB][NN][DD]
    const float* __restrict__ wih,   // [1024][256]
    const float* __restrict__ whh,   // [1024][256]
    const float* __restrict__ bih,   // [1024]
    const float* __restrict__ bhh,   // [1024]
    const float* __restrict__ dwv,   // done_w [256]
    const float* __restrict__ dbp,   // done_b scalar
    const float* __restrict__ rpp,   // revisit_penalty scalar
    const float* __restrict__ keys,  // [NB][NN][DD]  (in d_ws)
    float* __restrict__ out)         // tours [NB][31] then logps [NB][31]
{
    __shared__ float xcat[RPB][512];    // [r][0:256]=inp, [256:512]=h
    __shared__ float cst[RPB][DD];
    __shared__ float wt[512 * 32];      // W tile: 512 cols x 32 k, XOR quad-swizzled
    __shared__ unsigned vis[RPB];
    __shared__ int uniq[RPB];
    __shared__ int firstn[RPB];
    __shared__ int compl_[RPB];

    const int t    = threadIdx.x;
    const int b0   = blockIdx.x * RPB;
    const int mg   = t >> 7;      // 0..3 -> rows mg*4 .. mg*4+3
    const int ni3  = t & 127;     // d-column within 128-group
    const int w    = t >> 6;      // wave 0..7
    const int lane = t & 63;

    const float done_b = dbp[0];
    const float rp     = rpp[0];

    // gate-column biases for this thread: j = {0,128,256,384,512,640,768,896} + ni3
    float bsv[8];
#pragma unroll
    for (int g = 0; g < 8; ++g) {
        const int j = (g >> 1) * 256 + ((g & 1) << 7) + ni3;
        bsv[g] = bih[j] + bhh[j];
    }
    // reorder to [i_d0,i_d1,f_d0,f_d1,g_d0,g_d1,o_d0,o_d1] layout used below
    // (bsv[g] above: g=0->j=ni3 (i,d0), g=1->ni3+128 (i,d1), g=2->256+ni3 (f,d0), ...)
    // which is already the layout we want.

    // ---- init: h=0, c=0, inp = mean over nodes, meta = 0 ----
    for (int idx = t; idx < RPB * DD; idx += NTHR) {
        const int r = idx >> 8, d = idx & 255;
        xcat[r][256 + d] = 0.0f;
        cst[r][d] = 0.0f;
    }
#pragma unroll
    for (int rr = 0; rr < 2; ++rr) {
        const int r = w * 2 + rr;
        const int b = b0 + r;
        float sx = 0.f, sy = 0.f, sz = 0.f, sw = 0.f;
        for (int n = 0; n < NN; ++n) {
            const float4 v = *(const float4*)&ne[((size_t)b * NN + n) * DD + lane * 4];
            sx += v.x; sy += v.y; sz += v.z; sw += v.w;
        }
        float4 m4;
        m4.x = sx / 20.0f; m4.y = sy / 20.0f; m4.z = sz / 20.0f; m4.w = sw / 20.0f;
        *(float4*)&xcat[r][lane * 4] = m4;
    }
    if (t < RPB) { vis[t] = 0u; uniq[t] = 0; firstn[t] = 0; compl_[t] = 0; }
    __syncthreads();

    auto stage = [&](int half, int k0) {
        __syncthreads();  // wt free (previous chunk consumed) + xcat/h writes visible
        const float* base = (k0 < 256) ? (wih + k0) : (whh + (k0 - 256));
        const int rl = t >> 3;
        const int q4 = t & 7;
#pragma unroll
        for (int p = 0; p < 8; ++p) {
            const int row = rl + (p << 6);
            const float4 v = *(const float4*)&base[(size_t)(half * 512 + row) * DD + (q4 << 2)];
            *(float4*)&wt[(row << 5) + ((q4 ^ (row & 7)) << 2)] = v;
        }
        __syncthreads();  // wt ready
    };

    auto gemm_chunk = [&](int k0, float (&acc)[4][4]) {
#pragma unroll
        for (int q = 0; q < 8; ++q) {
            float4 av[4];
#pragma unroll
            for (int i = 0; i < 4; ++i)
                av[i] = *(const float4*)&xcat[(mg << 2) + i][k0 + (q << 2)];
            float4 wv[4];
#pragma unroll
            for (int c = 0; c < 4; ++c) {
                const int row = ni3 + (c << 7);
                wv[c] = *(const float4*)&wt[(row << 5) + ((q ^ (row & 7)) << 2)];
            }
#pragma unroll
            for (int i = 0; i < 4; ++i)
#pragma unroll
                for (int c = 0; c < 4; ++c) {
                    acc[i][c] = fmaf(av[i].x, wv[c].x, acc[i][c]);
                    acc[i][c] = fmaf(av[i].y, wv[c].y, acc[i][c]);
                    acc[i][c] = fmaf(av[i].z, wv[c].z, acc[i][c]);
                    acc[i][c] = fmaf(av[i].w, wv[c].w, acc[i][c]);
                }
        }
    };

    for (int step = 0; step < TST; ++step) {
        // ---- gate GEMM: acc0 -> gate cols [0,512) (i,f); acc1 -> [512,1024) (g,o)
        float acc0[4][4] = {};
        float acc1[4][4] = {};
#pragma unroll 1
        for (int kc = 0; kc < 16; ++kc) { stage(0, kc * 32); gemm_chunk(kc * 32, acc0); }
#pragma unroll 1
        for (int kc = 0; kc < 16; ++kc) { stage(1, kc * 32); gemm_chunk(kc * 32, acc1); }
        __syncthreads();  // all GEMM reads of xcat done before h2 overwrite

        // ---- LSTM elementwise: this thread owns rows mg*4..+3, d in {ni3, ni3+128}
#pragma unroll
        for (int i = 0; i < 4; ++i) {
            const int r = (mg << 2) + i;
#pragma unroll
            for (int dd = 0; dd < 2; ++dd) {
                const int d = ni3 + (dd << 7);
                const float gi = acc0[i][dd]     + bsv[0 + dd];
                const float gf = acc0[i][2 + dd] + bsv[2 + dd];
                const float gg = acc1[i][dd]     + bsv[4 + dd];
                const float go = acc1[i][2 + dd] + bsv[6 + dd];
                const float co = cst[r][d];
                const float cn = sigf(gf) * co + sigf(gi) * tanhf(gg);
                const float hn = sigf(go) * tanhf(cn);
                cst[r][d] = cn;
                xcat[r][256 + d] = hn;
            }
        }
        __syncthreads();  // h2 ready for scoring

        // ---- per-row: done predictor, pointer scores, softmax/argmax, update
#pragma unroll
        for (int rr = 0; rr < 2; ++rr) {
            const int r = w * 2 + rr;
            const int b = b0 + r;
            const float4 h4 = *(const float4*)&xcat[r][256 + lane * 4];

            // done dot
            const float4 dv = *(const float4*)&dwv[lane * 4];
            float pd = h4.x * dv.x + h4.y * dv.y + h4.z * dv.z + h4.w * dv.w;
#pragma unroll
            for (int o = 32; o >= 1; o >>= 1) pd += __shfl_xor(pd, o);

            // pointer scores: lane n keeps score for node n
            float myscore = 0.0f;
            for (int n = 0; n < NN; ++n) {
                const float4 kv = *(const float4*)&keys[((size_t)b * NN + n) * DD + lane * 4];
                float sc = h4.x * kv.x + h4.y * kv.y + h4.z * kv.z + h4.w * kv.w;
#pragma unroll
                for (int o = 32; o >= 1; o >>= 1) sc += __shfl_xor(sc, o);
                if (lane == n) myscore = sc;
            }

            const unsigned vm0 = vis[r];
            int un = uniq[r];
            int fn = firstn[r];
            const int cm = compl_[r];

            const float dprob = 1.0f / (1.0f + expf(-(pd + done_b)));
            const int eligible = (!cm) && (un >= NN) && (step >= NN);
            const int cm2 = cm || (eligible && (dprob > 0.5f));

            float s;
            if (lane < NN) {
                s = myscore * SCALE;
                if ((!cm2) && (un < NN) && ((vm0 >> lane) & 1u)) s = rp;
                if (cm2) s = (lane == fn) ? 100.0f : -1e9f;
            } else {
                s = -INFINITY;
            }
            float m = s;
#pragma unroll
            for (int o = 32; o >= 1; o >>= 1) m = fmaxf(m, __shfl_xor(m, o));
            const float e = (lane < NN) ? expf(s - m) : 0.0f;
            float se = e;
#pragma unroll
            for (int o = 32; o >= 1; o >>= 1) se += __shfl_xor(se, o);
            const float p = e / se;                 // IEEE div, matches softmax
            float pm = p;
#pragma unroll
            for (int o = 32; o >= 1; o >>= 1) pm = fmaxf(pm, __shfl_xor(pm, o));
            const unsigned long long bal = __ballot(p == pm);
            const int choice = __ffsll(bal) - 1;    // first index of max prob
            const int curr = cm2 ? fn : choice;
            const float pc = __shfl(p, curr);
            const float lp = logf(pc + 1e-10f);

            if (step == 0) fn = curr;
            const int newly = (!cm2) && !((vm0 >> curr) & 1u);
            unsigned vm = vm0;
            if (!cm2) vm |= (1u << curr);
            un += newly;

            if (lane == 0) {
                vis[r] = vm; uniq[r] = un; firstn[r] = fn; compl_[r] = cm2;
                out[(size_t)b * (TST + 1) + step] = (float)curr;
                out[(size_t)NB * (TST + 1) + (size_t)b * (TST + 1) + step] = lp;
            }
            // gather next input (node_emb[b, curr])
            const float4 nv = *(const float4*)&ne[((size_t)b * NN + curr) * DD + lane * 4];
            *(float4*)&xcat[r][lane * 4] = nv;
        }
        // next iteration's first stage() barrier orders these writes
    }

    __syncthreads();
    if (t < RPB) {
        const int b = b0 + t;
        out[(size_t)b * (TST + 1) + TST] = compl_[t] ? 0.0f : (float)firstn[t];
        out[(size_t)NB * (TST + 1) + (size_t)b * (TST + 1) + TST] = 0.0f;
    }
}

// ---------------------------------------------------------------------------
extern "C" void kernel_launch(void* const* d_in, const int* in_sizes, int n_in,
                              void* d_out, int out_size, void* d_ws, size_t ws_size,
                              hipStream_t stream) {
    (void)in_sizes; (void)n_in; (void)out_size;
    const float* ne  = (const float*)d_in[0];
    // d_in[1] = mask (unused by forward)
    const float* wih = (const float*)d_in[2];
    const float* whh = (const float*)d_in[3];
    const float* bih = (const float*)d_in[4];
    const float* bhh = (const float*)d_in[5];
    const float* aw  = (const float*)d_in[6];
    const float* ab  = (const float*)d_in[7];
    const float* dw  = (const float*)d_in[8];
    const float* db  = (const float*)d_in[9];
    const float* rp  = (const float*)d_in[10];
    // d_in[11] = greedy (always greedy path)
    float* out  = (float*)d_out;
    float* keys = (float*)d_ws;           // [NB*NN*DD] floats = 80 MB
    if (ws_size < (size_t)NB * NN * DD * sizeof(float)) return;

    keys_gemm<<<dim3((NB * NN) / 64, DD / 64), 256, 0, stream>>>(ne, aw, ab, keys);
    decode<<<dim3(NB / RPB), NTHR, 0, stream>>>(ne, wih, whh, bih, bhh, dw, db, rp, keys, out);
}